// Round 2
// baseline (21.840 us; speedup 1.0000x reference)
//
#include <hip/hip_runtime.h>

#if __has_builtin(__builtin_amdgcn_exp2f)
#define EXP2F(x) __builtin_amdgcn_exp2f(x)
#else
#define EXP2F(x) exp2f(x)
#endif

constexpr float L2E = 1.4426950408889634f;
constexpr float CD  = -500.0f * L2E;   // -0.5/0.001 * log2(e)

// Per-Gaussian expanded coefficients (8 floats in d_ws):
//   exponent(log2 domain) = c0*px^2 + c1*py^2 + c2*px + c3*py + c4*dx + c5*dy + c6 + K
// where K = CD*(dx^2+dy^2) is per-point.
__global__ __launch_bounds__(256)
void prep_kernel(const float* __restrict__ latents, float* __restrict__ cf, int M)
{
    int j = blockIdx.x * blockDim.x + threadIdx.x;
    if (j >= M) return;
    const float* L = latents + j * 6;
    float2 m01 = *(const float2*)(L);       // mx, my
    float2 m23 = *(const float2*)(L + 2);   // mdx, mdy
    float2 s01 = *(const float2*)(L + 4);   // raw sigma_x, sigma_y
    float A = (-0.5f * L2E) / (fmaxf(s01.x, 0.0f) + 0.01f);
    float B = (-0.5f * L2E) / (fmaxf(s01.y, 0.0f) + 0.01f);
    float mx = m01.x, my = m01.y, mdx = m23.x, mdy = m23.y;
    float c6 = A*mx*mx + B*my*my + CD*(mdx*mdx + mdy*mdy);
    ((float4*)cf)[j*2]     = make_float4(A, B, -2.0f*A*mx, -2.0f*B*my);
    ((float4*)cf)[j*2 + 1] = make_float4(-2.0f*CD*mdx, -2.0f*CD*mdy, c6, 0.0f);
}

// Block = 256 threads = 4 waves. Each block covers 64 points; wave w sums
// Gaussian chunk w (M/4 each). Coefficients are wave-uniform -> s_load (SGPR),
// zero LDS in the inner loop.
__global__ __launch_bounds__(256)
void decoder_kernel(const float* __restrict__ origins,
                    const float* __restrict__ directions,
                    const float* __restrict__ cf,
                    float* __restrict__ out, int N, int M)
{
    __shared__ float psum[256];
    const int tid  = threadIdx.x;
    const int lane = tid & 63;
    const int part = tid >> 6;            // 0..3, wave-uniform
    const int i    = blockIdx.x * 64 + lane;
    const int ii   = (i < N) ? i : (N > 0 ? N - 1 : 0);

    const float2 o = ((const float2*)origins)[ii];
    const float2 d = ((const float2*)directions)[ii];
    const float px = o.x, py = o.y, dx = d.x, dy = d.y;
    const float qx = px * px, qy = py * py;
    const float K  = CD * fmaf(dy, dy, dx * dx);

    const int chunk = (M + 3) >> 2;
    int jb = part * chunk;
    int je = jb + chunk; if (je > M) je = M;
    jb = __builtin_amdgcn_readfirstlane(jb);   // force uniform -> s_load
    je = __builtin_amdgcn_readfirstlane(je);

    const float4* __restrict__ c4p = (const float4*)cf;

    float s0 = 0.0f, s1 = 0.0f, s2 = 0.0f, s3 = 0.0f;

    auto term = [&](int j) -> float {
        float4 a = c4p[j * 2];
        float4 b = c4p[j * 2 + 1];
        float e = b.z + K;
        e = fmaf(b.y, dy, e);
        e = fmaf(b.x, dx, e);
        e = fmaf(a.w, py, e);
        e = fmaf(a.z, px, e);
        e = fmaf(a.y, qy, e);
        e = fmaf(a.x, qx, e);
        return EXP2F(e);
    };

    int j = jb;
    for (; j + 4 <= je; j += 4) {
        s0 += term(j + 0);
        s1 += term(j + 1);
        s2 += term(j + 2);
        s3 += term(j + 3);
    }
    for (; j < je; ++j) s0 += term(j);

    psum[tid] = (s0 + s1) + (s2 + s3);
    __syncthreads();

    if (tid < 64 && i < N) {
        float tot = (psum[tid] + psum[tid + 64]) +
                    (psum[tid + 128] + psum[tid + 192]);
        out[i] = fminf(fmaxf(tot, 0.0f), 1.0f);
    }
}

extern "C" void kernel_launch(void* const* d_in, const int* in_sizes, int n_in,
                              void* d_out, int out_size, void* d_ws, size_t ws_size,
                              hipStream_t stream) {
    const float* origins    = (const float*)d_in[0];
    const float* directions = (const float*)d_in[1];
    const float* latents    = (const float*)d_in[2];
    float* out = (float*)d_out;
    float* cf  = (float*)d_ws;   // M * 8 floats

    int N = in_sizes[0] / 2;
    int M = in_sizes[2] / 6;

    int pblocks = (M + 255) / 256;
    prep_kernel<<<pblocks, 256, 0, stream>>>(latents, cf, M);

    int nblocks = (N + 63) / 64;
    decoder_kernel<<<nblocks, 256, 0, stream>>>(origins, directions, cf, out, N, M);
}

// Round 3
// 20.431 us; speedup vs baseline: 1.0690x; 1.0690x over previous
//
#include <hip/hip_runtime.h>

#if __has_builtin(__builtin_amdgcn_exp2f)
#define EXP2F(x) __builtin_amdgcn_exp2f(x)
#else
#define EXP2F(x) exp2f(x)
#endif

typedef float v2f __attribute__((ext_vector_type(2)));

constexpr float L2E = 1.4426950408889634f;
constexpr float CD  = -500.0f * L2E;   // -0.5/0.001 * log2(e)

static __device__ __forceinline__ v2f mk2(float x, float y) {
    v2f r; r.x = x; r.y = y; return r;
}

// Pair-transposed coefficients: for Gaussian pair p (j=2p, 2p+1), 16 floats:
//   f4[0] = (c0_0, c0_1, c1_0, c1_1)   qx, qy weights
//   f4[1] = (c2_0, c2_1, c3_0, c3_1)   px, py weights
//   f4[2] = (c4_0, c4_1, c5_0, c5_1)   dx, dy weights
//   f4[3] = (c6_0, c6_1, 0, 0)         constant
// exponent(log2) = c0*px^2 + c1*py^2 + c2*px + c3*py + c4*dx + c5*dy + c6 + K
__global__ __launch_bounds__(256)
void prep_kernel(const float* __restrict__ latents, float* __restrict__ cf,
                 int M, int P)
{
    int p = blockIdx.x * blockDim.x + threadIdx.x;
    if (p >= P) return;
    float c[2][7];
    #pragma unroll
    for (int h = 0; h < 2; ++h) {
        int j = 2 * p + h;
        if (j < M) {
            const float* L = latents + j * 6;
            float mx = L[0], my = L[1], mdx = L[2], mdy = L[3];
            float A = (-0.5f * L2E) / (fmaxf(L[4], 0.0f) + 0.01f);
            float B = (-0.5f * L2E) / (fmaxf(L[5], 0.0f) + 0.01f);
            c[h][0] = A;
            c[h][1] = B;
            c[h][2] = -2.0f * A * mx;
            c[h][3] = -2.0f * B * my;
            c[h][4] = -2.0f * CD * mdx;
            c[h][5] = -2.0f * CD * mdy;
            c[h][6] = A*mx*mx + B*my*my + CD*(mdx*mdx + mdy*mdy);
        } else {
            c[h][0] = c[h][1] = c[h][2] = c[h][3] = c[h][4] = c[h][5] = 0.0f;
            c[h][6] = -3.0e38f;   // exp2 -> 0, padded slot contributes nothing
        }
    }
    float4* o = (float4*)(cf + (size_t)p * 16);
    o[0] = make_float4(c[0][0], c[1][0], c[0][1], c[1][1]);
    o[1] = make_float4(c[0][2], c[1][2], c[0][3], c[1][3]);
    o[2] = make_float4(c[0][4], c[1][4], c[0][5], c[1][5]);
    o[3] = make_float4(c[0][6], c[1][6], 0.0f, 0.0f);
}

// Block = 512 threads = 8 waves; 64 points/block; wave w handles pair-chunk w.
// Grid 1024 blocks -> 4 blocks/CU -> 32 waves/CU (max occupancy).
__global__ __launch_bounds__(512, 8)
void decoder_kernel(const float* __restrict__ origins,
                    const float* __restrict__ directions,
                    const float* __restrict__ cf,
                    float* __restrict__ out, int N, int P)
{
    __shared__ float psum[512];
    const int tid  = threadIdx.x;
    const int lane = tid & 63;
    const int part = tid >> 6;            // 0..7, wave-uniform
    const int i    = blockIdx.x * 64 + lane;
    const int ii   = (i < N) ? i : (N > 0 ? N - 1 : 0);

    const float2 o = ((const float2*)origins)[ii];
    const float2 d = ((const float2*)directions)[ii];
    const float K  = CD * fmaf(d.y, d.y, d.x * d.x);
    const v2f px2 = mk2(o.x, o.x), py2 = mk2(o.y, o.y);
    const v2f qx2 = mk2(o.x*o.x, o.x*o.x), qy2 = mk2(o.y*o.y, o.y*o.y);
    const v2f dx2 = mk2(d.x, d.x), dy2 = mk2(d.y, d.y);
    const v2f K2  = mk2(K, K);

    const int chunk = (P + 7) >> 3;
    int pb = part * chunk;
    int pe = pb + chunk; if (pe > P) pe = P;
    pb = __builtin_amdgcn_readfirstlane(pb);
    pe = __builtin_amdgcn_readfirstlane(pe);

    const float4* __restrict__ c4p = (const float4*)cf;

    v2f acc0 = mk2(0.0f, 0.0f), acc1 = mk2(0.0f, 0.0f);

    #pragma unroll 2
    for (int p = pb; p < pe; ++p) {
        float4 a0 = c4p[4*p + 0];
        float4 a1 = c4p[4*p + 1];
        float4 a2 = c4p[4*p + 2];
        float4 a3 = c4p[4*p + 3];
        v2f e = mk2(a3.x, a3.y) + K2;
        e = __builtin_elementwise_fma(mk2(a0.x, a0.y), qx2, e);
        e = __builtin_elementwise_fma(mk2(a0.z, a0.w), qy2, e);
        e = __builtin_elementwise_fma(mk2(a1.x, a1.y), px2, e);
        e = __builtin_elementwise_fma(mk2(a1.z, a1.w), py2, e);
        e = __builtin_elementwise_fma(mk2(a2.x, a2.y), dx2, e);
        e = __builtin_elementwise_fma(mk2(a2.z, a2.w), dy2, e);
        v2f x = mk2(EXP2F(e.x), EXP2F(e.y));
        if (p & 1) acc1 += x; else acc0 += x;
    }

    v2f accs = acc0 + acc1;
    psum[tid] = accs.x + accs.y;
    __syncthreads();

    if (tid < 64 && i < N) {
        float t = 0.0f;
        #pragma unroll
        for (int k = 0; k < 8; ++k) t += psum[lane + 64*k];
        out[i] = fminf(fmaxf(t, 0.0f), 1.0f);
    }
}

extern "C" void kernel_launch(void* const* d_in, const int* in_sizes, int n_in,
                              void* d_out, int out_size, void* d_ws, size_t ws_size,
                              hipStream_t stream) {
    const float* origins    = (const float*)d_in[0];
    const float* directions = (const float*)d_in[1];
    const float* latents    = (const float*)d_in[2];
    float* out = (float*)d_out;
    float* cf  = (float*)d_ws;    // P * 16 floats

    int N = in_sizes[0] / 2;
    int M = in_sizes[2] / 6;
    int P = (M + 1) / 2;          // Gaussian pairs (padded)

    int pblocks = (P + 255) / 256;
    prep_kernel<<<pblocks, 256, 0, stream>>>(latents, cf, M, P);

    int nblocks = (N + 63) / 64;
    decoder_kernel<<<nblocks, 512, 0, stream>>>(origins, directions, cf, out, N, P);
}

// Round 4
// 16.447 us; speedup vs baseline: 1.3279x; 1.2422x over previous
//
#include <hip/hip_runtime.h>

#if __has_builtin(__builtin_amdgcn_exp2f)
#define EXP2F(x) __builtin_amdgcn_exp2f(x)
#else
#define EXP2F(x) exp2f(x)
#endif

typedef float v2f __attribute__((ext_vector_type(2)));

constexpr float L2E = 1.4426950408889634f;
constexpr float CD  = -500.0f * L2E;   // -0.5/0.001 * log2(e)
#define MAXP 256                       // max Gaussian pairs (M <= 512)

static __device__ __forceinline__ v2f mk2(float x, float y) {
    v2f r; r.x = x; r.y = y; return r;
}

// Single fused kernel. Block = 512 threads = 8 waves, covers 64 points.
// Phase 1: threads 0..P-1 each expand one Gaussian PAIR into LDS
//          (pair-transposed coefficients, 4 x float4 per pair).
// Phase 2: wave w sums pair-chunk w (P/8 pairs) for its 64 points via
//          broadcast ds_read_b128 (wave-uniform address -> conflict-free).
// exponent(log2) = c0*px^2 + c1*py^2 + c2*px + c3*py + c4*dx + c5*dy + c6 + K
__global__ __launch_bounds__(512, 8)
void decoder_fused(const float* __restrict__ origins,
                   const float* __restrict__ directions,
                   const float* __restrict__ latents,
                   float* __restrict__ out, int N, int M, int P)
{
    __shared__ float4 lcf[MAXP * 4];
    __shared__ float  psum[512];

    const int tid = threadIdx.x;

    // ---- Phase 1: expand coefficients into LDS (once per block) ----
    if (tid < P) {
        float c[2][7];
        #pragma unroll
        for (int h = 0; h < 2; ++h) {
            int j = 2 * tid + h;
            if (j < M) {
                const float* L = latents + j * 6;
                float mx = L[0], my = L[1], mdx = L[2], mdy = L[3];
                float A = (-0.5f * L2E) / (fmaxf(L[4], 0.0f) + 0.01f);
                float B = (-0.5f * L2E) / (fmaxf(L[5], 0.0f) + 0.01f);
                c[h][0] = A;
                c[h][1] = B;
                c[h][2] = -2.0f * A * mx;
                c[h][3] = -2.0f * B * my;
                c[h][4] = -2.0f * CD * mdx;
                c[h][5] = -2.0f * CD * mdy;
                c[h][6] = A*mx*mx + B*my*my + CD*(mdx*mdx + mdy*mdy);
            } else {
                c[h][0] = c[h][1] = c[h][2] = c[h][3] = c[h][4] = c[h][5] = 0.0f;
                c[h][6] = -3.0e38f;   // exp2 -> 0: padded slot contributes 0
            }
        }
        lcf[tid*4 + 0] = make_float4(c[0][0], c[1][0], c[0][1], c[1][1]);
        lcf[tid*4 + 1] = make_float4(c[0][2], c[1][2], c[0][3], c[1][3]);
        lcf[tid*4 + 2] = make_float4(c[0][4], c[1][4], c[0][5], c[1][5]);
        lcf[tid*4 + 3] = make_float4(c[0][6], c[1][6], 0.0f, 0.0f);
    }

    // ---- Per-point setup (overlaps with LDS writes draining) ----
    const int lane = tid & 63;
    const int part = tid >> 6;            // 0..7, wave-uniform
    const int i    = blockIdx.x * 64 + lane;
    const int ii   = (i < N) ? i : (N > 0 ? N - 1 : 0);

    const float2 o = ((const float2*)origins)[ii];
    const float2 d = ((const float2*)directions)[ii];
    const float K  = CD * fmaf(d.y, d.y, d.x * d.x);
    const v2f px2 = mk2(o.x, o.x), py2 = mk2(o.y, o.y);
    const v2f qx2 = mk2(o.x*o.x, o.x*o.x), qy2 = mk2(o.y*o.y, o.y*o.y);
    const v2f dx2 = mk2(d.x, d.x), dy2 = mk2(d.y, d.y);
    const v2f K2  = mk2(K, K);

    __syncthreads();

    // ---- Phase 2: sum this wave's pair-chunk ----
    const int chunk = (P + 7) >> 3;
    int pb = part * chunk;
    int pe = pb + chunk; if (pe > P) pe = P;
    pb = __builtin_amdgcn_readfirstlane(pb);
    pe = __builtin_amdgcn_readfirstlane(pe);

    v2f acc0 = mk2(0.0f, 0.0f), acc1 = mk2(0.0f, 0.0f);

    #pragma unroll 2
    for (int p = pb; p < pe; ++p) {
        float4 a0 = lcf[4*p + 0];
        float4 a1 = lcf[4*p + 1];
        float4 a2 = lcf[4*p + 2];
        float4 a3 = lcf[4*p + 3];
        v2f e = mk2(a3.x, a3.y) + K2;
        e = __builtin_elementwise_fma(mk2(a0.x, a0.y), qx2, e);
        e = __builtin_elementwise_fma(mk2(a0.z, a0.w), qy2, e);
        e = __builtin_elementwise_fma(mk2(a1.x, a1.y), px2, e);
        e = __builtin_elementwise_fma(mk2(a1.z, a1.w), py2, e);
        e = __builtin_elementwise_fma(mk2(a2.x, a2.y), dx2, e);
        e = __builtin_elementwise_fma(mk2(a2.z, a2.w), dy2, e);
        v2f x = mk2(EXP2F(e.x), EXP2F(e.y));
        if (p & 1) acc1 += x; else acc0 += x;
    }

    v2f accs = acc0 + acc1;
    psum[tid] = accs.x + accs.y;
    __syncthreads();

    if (tid < 64 && i < N) {
        float t = 0.0f;
        #pragma unroll
        for (int k = 0; k < 8; ++k) t += psum[lane + 64*k];
        out[i] = fminf(fmaxf(t, 0.0f), 1.0f);
    }
}

extern "C" void kernel_launch(void* const* d_in, const int* in_sizes, int n_in,
                              void* d_out, int out_size, void* d_ws, size_t ws_size,
                              hipStream_t stream) {
    const float* origins    = (const float*)d_in[0];
    const float* directions = (const float*)d_in[1];
    const float* latents    = (const float*)d_in[2];
    float* out = (float*)d_out;

    int N = in_sizes[0] / 2;
    int M = in_sizes[2] / 6;
    if (M > 2 * MAXP) M = 2 * MAXP;   // problem spec: M = 512
    int P = (M + 1) / 2;              // Gaussian pairs (padded)

    int nblocks = (N + 63) / 64;
    decoder_fused<<<nblocks, 512, 0, stream>>>(origins, directions, latents,
                                               out, N, M, P);
}

// Round 5
// 14.440 us; speedup vs baseline: 1.5125x; 1.1390x over previous
//
#include <hip/hip_runtime.h>

#if __has_builtin(__builtin_amdgcn_exp2f)
#define EXP2F(x) __builtin_amdgcn_exp2f(x)
#else
#define EXP2F(x) exp2f(x)
#endif

typedef float v2f __attribute__((ext_vector_type(2)));

constexpr float L2E = 1.4426950408889634f;
constexpr float CD  = -500.0f * L2E;   // -0.5/0.001 * log2(e)
#define MAXP 256                       // max Gaussian pairs (M <= 512)

static __device__ __forceinline__ v2f mk2(float x, float y) {
    v2f r; r.x = x; r.y = y; return r;
}

// Single fused kernel. Block = 512 threads = 8 waves, covers 128 points
// (2 points per thread -> each coefficient ds_read feeds 2 points).
// Phase 1: threads 0..P-1 each expand one Gaussian PAIR into LDS
//          (pair-transposed coefficients, 4 x float4 per pair).
// Phase 2: wave w sums pair-chunk w (P/8 pairs) for its 2x64 points via
//          broadcast ds_read_b128 (wave-uniform address -> conflict-free).
// exponent(log2) = c0*px^2 + c1*py^2 + c2*px + c3*py + c4*dx + c5*dy + c6 + K
__global__ __launch_bounds__(512, 4)
void decoder_fused(const float* __restrict__ origins,
                   const float* __restrict__ directions,
                   const float* __restrict__ latents,
                   float* __restrict__ out, int N, int M, int P)
{
    __shared__ float4 lcf[MAXP * 4];
    __shared__ float  psum[8 * 128];   // [wave][pt*64 + lane]

    const int tid = threadIdx.x;

    // ---- Phase 1: expand coefficients into LDS (once per block) ----
    if (tid < P) {
        float c[2][7];
        #pragma unroll
        for (int h = 0; h < 2; ++h) {
            int j = 2 * tid + h;
            if (j < M) {
                const float* L = latents + j * 6;
                float mx = L[0], my = L[1], mdx = L[2], mdy = L[3];
                float A = (-0.5f * L2E) / (fmaxf(L[4], 0.0f) + 0.01f);
                float B = (-0.5f * L2E) / (fmaxf(L[5], 0.0f) + 0.01f);
                c[h][0] = A;
                c[h][1] = B;
                c[h][2] = -2.0f * A * mx;
                c[h][3] = -2.0f * B * my;
                c[h][4] = -2.0f * CD * mdx;
                c[h][5] = -2.0f * CD * mdy;
                c[h][6] = A*mx*mx + B*my*my + CD*(mdx*mdx + mdy*mdy);
            } else {
                c[h][0] = c[h][1] = c[h][2] = c[h][3] = c[h][4] = c[h][5] = 0.0f;
                c[h][6] = -3.0e38f;   // exp2 -> 0: padded slot contributes 0
            }
        }
        lcf[tid*4 + 0] = make_float4(c[0][0], c[1][0], c[0][1], c[1][1]);
        lcf[tid*4 + 1] = make_float4(c[0][2], c[1][2], c[0][3], c[1][3]);
        lcf[tid*4 + 2] = make_float4(c[0][4], c[1][4], c[0][5], c[1][5]);
        lcf[tid*4 + 3] = make_float4(c[0][6], c[1][6], 0.0f, 0.0f);
    }

    // ---- Per-point setup for 2 points ----
    const int lane = tid & 63;
    const int part = tid >> 6;            // 0..7, wave-uniform
    const int base = blockIdx.x * 128;
    const int i0   = base + lane;
    const int i1   = base + 64 + lane;
    const int ii0  = (i0 < N) ? i0 : (N > 0 ? N - 1 : 0);
    const int ii1  = (i1 < N) ? i1 : (N > 0 ? N - 1 : 0);

    const float2 oA = ((const float2*)origins)[ii0];
    const float2 dA = ((const float2*)directions)[ii0];
    const float2 oB = ((const float2*)origins)[ii1];
    const float2 dB = ((const float2*)directions)[ii1];

    const v2f pxA = mk2(oA.x, oA.x), pyA = mk2(oA.y, oA.y);
    const v2f qxA = pxA * pxA,        qyA = pyA * pyA;
    const v2f dxA = mk2(dA.x, dA.x), dyA = mk2(dA.y, dA.y);
    const float KA = CD * fmaf(dA.y, dA.y, dA.x * dA.x);
    const v2f KA2 = mk2(KA, KA);

    const v2f pxB = mk2(oB.x, oB.x), pyB = mk2(oB.y, oB.y);
    const v2f qxB = pxB * pxB,        qyB = pyB * pyB;
    const v2f dxB = mk2(dB.x, dB.x), dyB = mk2(dB.y, dB.y);
    const float KB = CD * fmaf(dB.y, dB.y, dB.x * dB.x);
    const v2f KB2 = mk2(KB, KB);

    __syncthreads();

    // ---- Phase 2: sum this wave's pair-chunk for both points ----
    const int chunk = (P + 7) >> 3;
    int pb = part * chunk;
    int pe = pb + chunk; if (pe > P) pe = P;
    pb = __builtin_amdgcn_readfirstlane(pb);
    pe = __builtin_amdgcn_readfirstlane(pe);

    v2f accA = mk2(0.0f, 0.0f), accB = mk2(0.0f, 0.0f);

    #pragma unroll 2
    for (int p = pb; p < pe; ++p) {
        float4 a0 = lcf[4*p + 0];
        float4 a1 = lcf[4*p + 1];
        float4 a2 = lcf[4*p + 2];
        float4 a3 = lcf[4*p + 3];
        v2f w0 = mk2(a0.x, a0.y), w1 = mk2(a0.z, a0.w);
        v2f w2 = mk2(a1.x, a1.y), w3 = mk2(a1.z, a1.w);
        v2f w4 = mk2(a2.x, a2.y), w5 = mk2(a2.z, a2.w);
        v2f w6 = mk2(a3.x, a3.y);

        v2f eA = w6 + KA2;
        eA = __builtin_elementwise_fma(w0, qxA, eA);
        eA = __builtin_elementwise_fma(w1, qyA, eA);
        eA = __builtin_elementwise_fma(w2, pxA, eA);
        eA = __builtin_elementwise_fma(w3, pyA, eA);
        eA = __builtin_elementwise_fma(w4, dxA, eA);
        eA = __builtin_elementwise_fma(w5, dyA, eA);

        v2f eB = w6 + KB2;
        eB = __builtin_elementwise_fma(w0, qxB, eB);
        eB = __builtin_elementwise_fma(w1, qyB, eB);
        eB = __builtin_elementwise_fma(w2, pxB, eB);
        eB = __builtin_elementwise_fma(w3, pyB, eB);
        eB = __builtin_elementwise_fma(w4, dxB, eB);
        eB = __builtin_elementwise_fma(w5, dyB, eB);

        accA += mk2(EXP2F(eA.x), EXP2F(eA.y));
        accB += mk2(EXP2F(eB.x), EXP2F(eB.y));
    }

    psum[part * 128 + lane]      = accA.x + accA.y;
    psum[part * 128 + 64 + lane] = accB.x + accB.y;
    __syncthreads();

    if (tid < 128) {
        int i = base + tid;
        if (i < N) {
            float t = 0.0f;
            #pragma unroll
            for (int k = 0; k < 8; ++k) t += psum[k * 128 + tid];
            out[i] = fminf(fmaxf(t, 0.0f), 1.0f);
        }
    }
}

extern "C" void kernel_launch(void* const* d_in, const int* in_sizes, int n_in,
                              void* d_out, int out_size, void* d_ws, size_t ws_size,
                              hipStream_t stream) {
    const float* origins    = (const float*)d_in[0];
    const float* directions = (const float*)d_in[1];
    const float* latents    = (const float*)d_in[2];
    float* out = (float*)d_out;

    int N = in_sizes[0] / 2;
    int M = in_sizes[2] / 6;
    if (M > 2 * MAXP) M = 2 * MAXP;   // problem spec: M = 512
    int P = (M + 1) / 2;              // Gaussian pairs (padded)

    int nblocks = (N + 127) / 128;
    decoder_fused<<<nblocks, 512, 0, stream>>>(origins, directions, latents,
                                               out, N, M, P);
}